// Round 11
// baseline (192.807 us; speedup 1.0000x reference)
//
#include <hip/hip_runtime.h>
#include <hip/hip_bf16.h>

#define B_TOTAL 262144
#define G 3
#define HD 256
#define HD2 128
#define ROWS 256
#define NTHREADS 1024
#define LDH 264   // bf16 stride; multiple of 8 keeps rows 16B-aligned for ds_read_b128

typedef short short8 __attribute__((ext_vector_type(8)));
typedef float floatx4 __attribute__((ext_vector_type(4)));

__device__ __forceinline__ unsigned short f2bf(float f) {
    unsigned u = __builtin_bit_cast(unsigned, f);
    u += 0x7FFFu + ((u >> 16) & 1u);   // RNE
    return (unsigned short)(u >> 16);
}

// Packed f32x2 -> bf16x2 (RNE). gfx950 has v_cvt_pk_bf16_f32 (1 instr).
__device__ __forceinline__ unsigned pack_bf16x2(float a, float b) {
#if __has_builtin(__builtin_amdgcn_cvt_pk_bf16_f32)
    auto r = __builtin_amdgcn_cvt_pk_bf16_f32(a, b);
    unsigned u;
    __builtin_memcpy(&u, &r, 4);
    return u;
#else
    return (unsigned)f2bf(a) | ((unsigned)f2bf(b) << 16);
#endif
}

__device__ __forceinline__ float fast_rcp(float x) {
#if __has_builtin(__builtin_amdgcn_rcpf)
    return __builtin_amdgcn_rcpf(x);
#else
    return 1.0f / x;
#endif
}
__device__ __forceinline__ float silu_f(float x) {
    return x * fast_rcp(1.0f + __expf(-x));
}

// ---- weight conversion: W1(pad K->32), W2, W3, W4(pad 3->16 rows) to bf16 ----
__global__ void convert_w_kernel(const float* __restrict__ W1, const float* __restrict__ W2,
                                 const float* __restrict__ W3, const float* __restrict__ W4,
                                 unsigned short* __restrict__ w1bf, unsigned short* __restrict__ w2bf,
                                 unsigned short* __restrict__ w3bf, unsigned short* __restrict__ w4bf) {
    int i = blockIdx.x * 256 + threadIdx.x;          // grid covers 65536
    if (i < HD * HD)  w2bf[i] = f2bf(W2[i]);
    if (i < HD2 * HD) w3bf[i] = f2bf(W3[i]);
    if (i < HD * 32) { int r = i >> 5, k = i & 31; w1bf[i] = (k < 7) ? f2bf(W1[r * 7 + k]) : (unsigned short)0; }
    if (i < 16 * HD2) { int r = i >> 7, k = i & 127; w4bf[i] = (r < G) ? f2bf(W4[r * HD2 + k]) : (unsigned short)0; }
}

__global__ __launch_bounds__(NTHREADS, 4) void mlp_kernel(
    const float* __restrict__ log_p, const float* __restrict__ log_y,
    const float* __restrict__ log_xb, const float* __restrict__ log_q,
    const float* __restrict__ b1, const float* __restrict__ b2,
    const float* __restrict__ b3, const float* __restrict__ b4,
    const float* __restrict__ p_log_beta, const float* __restrict__ p_log_delta,
    const unsigned short* __restrict__ w1bf, const unsigned short* __restrict__ w2bf,
    const unsigned short* __restrict__ w3bf, const unsigned short* __restrict__ w4bf,
    float* __restrict__ out)
{
    __shared__ __align__(16) unsigned short hA[ROWS][LDH];    // 135168 B, reused h1->h2->h3
    __shared__ __align__(16) unsigned short x_bf[ROWS][8];    // 4096 B: only k=0..7 nonzero
    __shared__ __align__(16) float bias1_s[HD];               // 1024 B
    __shared__ __align__(16) float bias2_s[HD];               // 1024 B
    __shared__ __align__(16) float bias3_s[HD2];              // 512 B   -> total 141824 B, 1 block/CU

    const int tid  = threadIdx.x;
    const int lane = tid & 63;
    const int wv   = tid >> 6;     // 0..15
    const int quad = lane >> 4;
    const int l15  = lane & 15;
    const int row0 = blockIdx.x * ROWS;

    const float beta  = fminf(fmaxf(__expf(p_log_beta[0]), 0.5f), 20.0f);
    const float delta = fast_rcp(1.0f + __expf(-p_log_delta[0]));

    // ---- Phase A: stage biases + input rows (one thread per row, one uint4 store) ----
    if (tid < HD) { bias1_s[tid] = b1[tid]; bias2_s[tid] = b2[tid]; }
    if (tid < HD2) bias3_s[tid] = b3[tid];
    if (tid < ROWS) {
        const int r = row0 + tid;
        const float p0 = log_p[r * 3 + 0], p1 = log_p[r * 3 + 1], p2 = log_p[r * 3 + 2];
        const float y  = log_y[r];
        const float xb0 = delta * log_xb[r * 3 + 0] + (1.0f - delta) * log_q[r * 3 + 0];
        const float xb1 = delta * log_xb[r * 3 + 1] + (1.0f - delta) * log_q[r * 3 + 1];
        const float xb2 = delta * log_xb[r * 3 + 2] + (1.0f - delta) * log_q[r * 3 + 2];
        uint4 u0;
        u0.x = pack_bf16x2(p0, p1);
        u0.y = pack_bf16x2(p2, y);
        u0.z = pack_bf16x2(xb0, xb1);
        u0.w = pack_bf16x2(xb2, 0.0f);
        *(uint4*)&x_bf[tid][0] = u0;
    }
    __syncthreads();   // barrier 1

    // Epilogue helper (bias already folded into acc): lane holds 4 consecutive
    // hidden cols [n0..n0+3] of batch row m.
    #define EPILOGUE(ACC, M, N0)                                                   \
        {                                                                          \
            const float v0 = silu_f((ACC)[0]);                                     \
            const float v1 = silu_f((ACC)[1]);                                     \
            const float v2 = silu_f((ACC)[2]);                                     \
            const float v3 = silu_f((ACC)[3]);                                     \
            uint2 u; u.x = pack_bf16x2(v0, v1); u.y = pack_bf16x2(v2, v3);         \
            *(uint2*)&hA[(M)][(N0)] = u;                                           \
        }

    // ---- Layer 1 (MFMA, K=32, A=W1 B=x): wave owns hidden cols [wv*16, +16),
    //      all 256 rows, 4 chunk-passes of 4 M-tiles to cap live bx regs.
    {
        const int nbase = wv * 16;
        const short8 aw = *(const short8*)(w1bf + (nbase + l15) * 32 + quad * 8);
        const float4 bv = *(const float4*)&bias1_s[nbase + quad * 4];
        #pragma unroll
        for (int chunk = 0; chunk < 4; ++chunk) {
            short8 bx[4];
            #pragma unroll
            for (int mt = 0; mt < 4; ++mt) {
                if (quad == 0)
                    bx[mt] = *(const short8*)&x_bf[(chunk * 4 + mt) * 16 + l15][0];
                else
                    bx[mt] = (short8){0, 0, 0, 0, 0, 0, 0, 0};
            }
            #pragma unroll
            for (int mt = 0; mt < 4; ++mt) {
                floatx4 acc = (floatx4){bv.x, bv.y, bv.z, bv.w};
                acc = __builtin_amdgcn_mfma_f32_16x16x32_bf16(aw, bx[mt], acc, 0, 0, 0);
                EPILOGUE(acc, (chunk * 4 + mt) * 16 + l15, nbase + quad * 4);
            }
        }
    }
    __syncthreads();   // barrier 2: h1 complete

    // ---- Layer 2 (MFMA, K=256): wave owns hidden cols [wv*16, +16), 16 M-tiles.
    //      aw (global, L2-resident) double-buffered; bh chunked 4-at-a-time.
    {
        const int nbase = wv * 16;
        floatx4 acc[16];
        {
            const float4 bv = *(const float4*)&bias2_s[nbase + quad * 4];
            #pragma unroll
            for (int mt = 0; mt < 16; ++mt)
                acc[mt] = (floatx4){bv.x, bv.y, bv.z, bv.w};
        }
        short8 aw[2];
        aw[0] = *(const short8*)(w2bf + (nbase + l15) * HD + quad * 8);
        #pragma unroll
        for (int ks = 0; ks < 8; ++ks) {
            const int cur = ks & 1, nxt = cur ^ 1;
            if (ks < 7) {
                const int kb = (ks + 1) * 32 + quad * 8;
                aw[nxt] = *(const short8*)(w2bf + (nbase + l15) * HD + kb);
            }
            const int kb0 = ks * 32 + quad * 8;
            #pragma unroll
            for (int chunk = 0; chunk < 4; ++chunk) {
                short8 bh[4];
                #pragma unroll
                for (int m = 0; m < 4; ++m)
                    bh[m] = *(const short8*)&hA[(chunk * 4 + m) * 16 + l15][kb0];
                #pragma unroll
                for (int m = 0; m < 4; ++m)
                    acc[chunk * 4 + m] = __builtin_amdgcn_mfma_f32_16x16x32_bf16(
                        aw[cur], bh[m], acc[chunk * 4 + m], 0, 0, 0);
            }
        }
        __syncthreads();   // barrier 3: all reads of h1 done before overwriting hA with h2
        #pragma unroll
        for (int mt = 0; mt < 16; ++mt)
            EPILOGUE(acc[mt], mt * 16 + l15, nbase + quad * 4);
    }
    __syncthreads();   // barrier 4: h2 complete

    // ---- Layer 3 (MFMA, K=256): wave (g=wv&7, h=wv>>3) owns hidden cols
    //      [g*16,+16) x rows [h*128,+128) = 8 M-tiles ----
    {
        const int nbase = (wv & 7) * 16;
        const int mbase = (wv >> 3) * 128;
        floatx4 acc[8];
        {
            const float4 bv = *(const float4*)&bias3_s[nbase + quad * 4];
            #pragma unroll
            for (int mt = 0; mt < 8; ++mt)
                acc[mt] = (floatx4){bv.x, bv.y, bv.z, bv.w};
        }
        short8 aw[2];
        aw[0] = *(const short8*)(w3bf + (nbase + l15) * HD + quad * 8);
        #pragma unroll
        for (int ks = 0; ks < 8; ++ks) {
            const int cur = ks & 1, nxt = cur ^ 1;
            if (ks < 7) {
                const int kb = (ks + 1) * 32 + quad * 8;
                aw[nxt] = *(const short8*)(w3bf + (nbase + l15) * HD + kb);
            }
            const int kb0 = ks * 32 + quad * 8;
            #pragma unroll
            for (int chunk = 0; chunk < 2; ++chunk) {
                short8 bh[4];
                #pragma unroll
                for (int m = 0; m < 4; ++m)
                    bh[m] = *(const short8*)&hA[mbase + (chunk * 4 + m) * 16 + l15][kb0];
                #pragma unroll
                for (int m = 0; m < 4; ++m)
                    acc[chunk * 4 + m] = __builtin_amdgcn_mfma_f32_16x16x32_bf16(
                        aw[cur], bh[m], acc[chunk * 4 + m], 0, 0, 0);
            }
        }
        __syncthreads();   // barrier 5: all reads of h2 done before overwriting hA with h3
        #pragma unroll
        for (int mt = 0; mt < 8; ++mt)
            EPILOGUE(acc[mt], mbase + mt * 16 + l15, nbase + quad * 4);
    }
    __syncthreads();   // barrier 6: h3 complete

    // ---- Layer 4 + softmax (MFMA, K=128, A=W4pad B=h3): wave owns rows [wv*16, +16) ----
    {
        floatx4 acc;
        #pragma unroll
        for (int i = 0; i < 4; ++i) {
            const int rrow = quad * 4 + i;
            acc[i] = (rrow < G) ? b4[rrow] : 0.0f;
        }
        #pragma unroll
        for (int ks = 0; ks < 4; ++ks) {
            const int kb = ks * 32 + quad * 8;
            const short8 aw4 = *(const short8*)(w4bf + l15 * HD2 + kb);
            const short8 bh4 = *(const short8*)&hA[wv * 16 + l15][kb];
            acc = __builtin_amdgcn_mfma_f32_16x16x32_bf16(aw4, bh4, acc, 0, 0, 0);
        }
        if (lane < 16) {   // quad 0: regs 0..2 = logits 0..2 for batch row wv*16+l15
            const float l0 = acc[0] * beta;
            const float l1 = acc[1] * beta;
            const float l2 = acc[2] * beta;
            const float m  = fmaxf(l0, fmaxf(l1, l2));
            const float e0 = __expf(l0 - m), e1 = __expf(l1 - m), e2 = __expf(l2 - m);
            const float inv = fast_rcp(e0 + e1 + e2);
            const int r = row0 + wv * 16 + l15;
            out[r * 3 + 0] = e0 * inv;
            out[r * 3 + 1] = e1 * inv;
            out[r * 3 + 2] = e2 * inv;
        }
    }
    #undef EPILOGUE
}

extern "C" void kernel_launch(void* const* d_in, const int* in_sizes, int n_in,
                              void* d_out, int out_size, void* d_ws, size_t ws_size,
                              hipStream_t stream) {
    (void)in_sizes; (void)n_in; (void)out_size; (void)ws_size;
    const float* log_p  = (const float*)d_in[0];
    const float* log_y  = (const float*)d_in[1];
    const float* log_xb = (const float*)d_in[2];
    const float* log_q  = (const float*)d_in[3];
    const float* W1 = (const float*)d_in[4];
    const float* b1 = (const float*)d_in[5];
    const float* W2 = (const float*)d_in[6];
    const float* b2 = (const float*)d_in[7];
    const float* W3 = (const float*)d_in[8];
    const float* b3 = (const float*)d_in[9];
    const float* W4 = (const float*)d_in[10];
    const float* b4 = (const float*)d_in[11];
    const float* lb = (const float*)d_in[12];
    const float* ld = (const float*)d_in[13];

    unsigned short* w2bf = (unsigned short*)d_ws;      // 65536 elems
    unsigned short* w3bf = w2bf + HD * HD;             // 32768 elems
    unsigned short* w1bf = w3bf + HD2 * HD;            // 8192 elems
    unsigned short* w4bf = w1bf + HD * 32;             // 2048 elems  (total 212 KB)

    convert_w_kernel<<<256, 256, 0, stream>>>(W1, W2, W3, W4, w1bf, w2bf, w3bf, w4bf);
    mlp_kernel<<<B_TOTAL / ROWS, NTHREADS, 0, stream>>>(
        log_p, log_y, log_xb, log_q, b1, b2, b3, b4, lb, ld,
        w1bf, w2bf, w3bf, w4bf, (float*)d_out);
}

// Round 12
// 161.797 us; speedup vs baseline: 1.1917x; 1.1917x over previous
//
#include <hip/hip_runtime.h>
#include <hip/hip_bf16.h>

#define B_TOTAL 262144
#define G 3
#define HD 256
#define HD2 128
#define ROWS 128
#define NTHREADS 512
#define LDH 264   // bf16 stride; multiple of 8 keeps rows 16B-aligned for ds_read_b128

typedef short short8 __attribute__((ext_vector_type(8)));
typedef float floatx4 __attribute__((ext_vector_type(4)));

__device__ __forceinline__ unsigned short f2bf(float f) {
    unsigned u = __builtin_bit_cast(unsigned, f);
    u += 0x7FFFu + ((u >> 16) & 1u);   // RNE
    return (unsigned short)(u >> 16);
}

// Packed f32x2 -> bf16x2 (RNE). gfx950 has v_cvt_pk_bf16_f32 (1 instr).
__device__ __forceinline__ unsigned pack_bf16x2(float a, float b) {
#if __has_builtin(__builtin_amdgcn_cvt_pk_bf16_f32)
    auto r = __builtin_amdgcn_cvt_pk_bf16_f32(a, b);
    unsigned u;
    __builtin_memcpy(&u, &r, 4);
    return u;
#else
    return (unsigned)f2bf(a) | ((unsigned)f2bf(b) << 16);
#endif
}

__device__ __forceinline__ float fast_rcp(float x) {
#if __has_builtin(__builtin_amdgcn_rcpf)
    return __builtin_amdgcn_rcpf(x);
#else
    return 1.0f / x;
#endif
}
__device__ __forceinline__ float silu_f(float x) {
    return x * fast_rcp(1.0f + __expf(-x));
}

// ---- weight conversion: W1(pad K->32), W2, W3, W4(pad 3->16 rows) to bf16 ----
__global__ void convert_w_kernel(const float* __restrict__ W1, const float* __restrict__ W2,
                                 const float* __restrict__ W3, const float* __restrict__ W4,
                                 unsigned short* __restrict__ w1bf, unsigned short* __restrict__ w2bf,
                                 unsigned short* __restrict__ w3bf, unsigned short* __restrict__ w4bf) {
    int i = blockIdx.x * 256 + threadIdx.x;          // grid covers 65536
    if (i < HD * HD)  w2bf[i] = f2bf(W2[i]);
    if (i < HD2 * HD) w3bf[i] = f2bf(W3[i]);
    if (i < HD * 32) { int r = i >> 5, k = i & 31; w1bf[i] = (k < 7) ? f2bf(W1[r * 7 + k]) : (unsigned short)0; }
    if (i < 16 * HD2) { int r = i >> 7, k = i & 127; w4bf[i] = (r < G) ? f2bf(W4[r * HD2 + k]) : (unsigned short)0; }
}

__global__ __launch_bounds__(NTHREADS, 4) void mlp_kernel(
    const float* __restrict__ log_p, const float* __restrict__ log_y,
    const float* __restrict__ log_xb, const float* __restrict__ log_q,
    const float* __restrict__ b1, const float* __restrict__ b2,
    const float* __restrict__ b3, const float* __restrict__ b4,
    const float* __restrict__ p_log_beta, const float* __restrict__ p_log_delta,
    const unsigned short* __restrict__ w1bf, const unsigned short* __restrict__ w2bf,
    const unsigned short* __restrict__ w3bf, const unsigned short* __restrict__ w4bf,
    float* __restrict__ out)
{
    __shared__ __align__(16) unsigned short hA[ROWS][LDH];    // 67584 B, reused h1->h2->h3
    __shared__ __align__(16) unsigned short x_bf[ROWS][8];    // 2048 B: only k=0..7 nonzero
    __shared__ __align__(16) float bias1_s[HD];               // 1024 B
    __shared__ __align__(16) float bias2_s[HD];               // 1024 B
    __shared__ __align__(16) float bias3_s[HD2];              // 512 B   -> total 72192 B, 2 blocks/CU

    const int tid  = threadIdx.x;
    const int lane = tid & 63;
    const int wv   = tid >> 6;     // 0..7
    const int quad = lane >> 4;
    const int l15  = lane & 15;
    const int row0 = blockIdx.x * ROWS;

    const float beta  = fminf(fmaxf(__expf(p_log_beta[0]), 0.5f), 20.0f);
    const float delta = fast_rcp(1.0f + __expf(-p_log_delta[0]));

    // ---- Phase A: stage biases + input rows (one thread per row, one uint4 store) ----
    if (tid < HD) { bias1_s[tid] = b1[tid]; bias2_s[tid] = b2[tid]; }
    if (tid < HD2) bias3_s[tid] = b3[tid];
    if (tid < ROWS) {
        const int r = row0 + tid;
        const float p0 = log_p[r * 3 + 0], p1 = log_p[r * 3 + 1], p2 = log_p[r * 3 + 2];
        const float y  = log_y[r];
        const float xb0 = delta * log_xb[r * 3 + 0] + (1.0f - delta) * log_q[r * 3 + 0];
        const float xb1 = delta * log_xb[r * 3 + 1] + (1.0f - delta) * log_q[r * 3 + 1];
        const float xb2 = delta * log_xb[r * 3 + 2] + (1.0f - delta) * log_q[r * 3 + 2];
        uint4 u0;
        u0.x = pack_bf16x2(p0, p1);
        u0.y = pack_bf16x2(p2, y);
        u0.z = pack_bf16x2(xb0, xb1);
        u0.w = pack_bf16x2(xb2, 0.0f);
        *(uint4*)&x_bf[tid][0] = u0;
    }
    __syncthreads();   // barrier 1

    // Early-silu helper: silu+pack an acc tile into a uint2 (no LDS write).
    #define SILU_PACK(ACC)                                                          \
        (uint2){ pack_bf16x2(silu_f((ACC)[0]), silu_f((ACC)[1])),                   \
                 pack_bf16x2(silu_f((ACC)[2]), silu_f((ACC)[3])) }

    // ---- Layer 1 (MFMA, K=32, A=W1 B=x): wave owns hidden cols [wv*32, +32),
    //      all 128 rows, two half-passes. Epilogue writes h1 (x_bf disjoint).
    {
        const int nbase = wv * 32;
        short8 aw[2];
        #pragma unroll
        for (int nt = 0; nt < 2; ++nt)
            aw[nt] = *(const short8*)(w1bf + (nbase + nt * 16 + l15) * 32 + quad * 8);
        #pragma unroll
        for (int half = 0; half < 2; ++half) {
            short8 bx[4];
            #pragma unroll
            for (int mt = 0; mt < 4; ++mt) {
                if (quad == 0)
                    bx[mt] = *(const short8*)&x_bf[(half * 4 + mt) * 16 + l15][0];
                else
                    bx[mt] = (short8){0, 0, 0, 0, 0, 0, 0, 0};
            }
            #pragma unroll
            for (int nt = 0; nt < 2; ++nt) {
                const float4 bv = *(const float4*)&bias1_s[nbase + nt * 16 + quad * 4];
                #pragma unroll
                for (int mt = 0; mt < 4; ++mt) {
                    floatx4 acc = (floatx4){bv.x, bv.y, bv.z, bv.w};
                    acc = __builtin_amdgcn_mfma_f32_16x16x32_bf16(aw[nt], bx[mt], acc, 0, 0, 0);
                    const uint2 u = SILU_PACK(acc);
                    *(uint2*)&hA[(half * 4 + mt) * 16 + l15][nbase + nt * 16 + quad * 4] = u;
                }
            }
        }
    }

    // Prefetch layer-2 first aw frags: part of layer-2's working set, just held
    // earlier so the load is in flight across barrier 2 (hides post-barrier L2 latency).
    short8 aw2p[2];
    #pragma unroll
    for (int nt = 0; nt < 2; ++nt)
        aw2p[nt] = *(const short8*)(w2bf + (wv * 32 + nt * 16 + l15) * HD + quad * 8);

    __syncthreads();   // barrier 2: h1 complete

    // ---- Layer 2 (MFMA, K=256): wave owns hidden cols [wv*32, +32), 16 M-tiles.
    //      aw double-buffered; bh chunked 4-at-a-time; early silu before barrier 3.
    {
        const int nbase = wv * 32;
        floatx4 acc[8][2];
        #pragma unroll
        for (int nt = 0; nt < 2; ++nt) {
            const float4 bv = *(const float4*)&bias2_s[nbase + nt * 16 + quad * 4];
            #pragma unroll
            for (int mt = 0; mt < 8; ++mt)
                acc[mt][nt] = (floatx4){bv.x, bv.y, bv.z, bv.w};
        }
        short8 aw[2][2];
        aw[0][0] = aw2p[0];
        aw[0][1] = aw2p[1];
        #pragma unroll
        for (int ks = 0; ks < 8; ++ks) {
            const int cur = ks & 1, nxt = cur ^ 1;
            if (ks < 7) {
                const int kb = (ks + 1) * 32 + quad * 8;
                #pragma unroll
                for (int nt = 0; nt < 2; ++nt)
                    aw[nxt][nt] = *(const short8*)(w2bf + (nbase + nt * 16 + l15) * HD + kb);
            }
            const int kb0 = ks * 32 + quad * 8;
            #pragma unroll
            for (int chunk = 0; chunk < 2; ++chunk) {
                short8 bh[4];
                #pragma unroll
                for (int m = 0; m < 4; ++m)
                    bh[m] = *(const short8*)&hA[(chunk * 4 + m) * 16 + l15][kb0];
                #pragma unroll
                for (int m = 0; m < 4; ++m)
                    #pragma unroll
                    for (int nt = 0; nt < 2; ++nt)
                        acc[chunk * 4 + m][nt] = __builtin_amdgcn_mfma_f32_16x16x32_bf16(
                            aw[cur][nt], bh[m], acc[chunk * 4 + m][nt], 0, 0, 0);
            }
        }
        // Prefetch layer-3 first aw frag (in flight across barriers 3+4).
        short8 aw3p = *(const short8*)(w3bf + (wv * 16 + l15) * HD + quad * 8);
        // Early silu+pack (overlaps other waves' MFMA; acc dies into pk).
        uint2 pk[8][2];
        #pragma unroll
        for (int mt = 0; mt < 8; ++mt)
            #pragma unroll
            for (int nt = 0; nt < 2; ++nt)
                pk[mt][nt] = SILU_PACK(acc[mt][nt]);
        __syncthreads();   // barrier 3: all reads of h1 done
        #pragma unroll
        for (int mt = 0; mt < 8; ++mt)
            #pragma unroll
            for (int nt = 0; nt < 2; ++nt)
                *(uint2*)&hA[mt * 16 + l15][nbase + nt * 16 + quad * 4] = pk[mt][nt];
        __syncthreads();   // barrier 4: h2 complete

        // ---- Layer 3 (MFMA, K=256): wave owns hidden cols [wv*16, +16), 8 M-tiles ----
        const int nbase3 = wv * 16;
        floatx4 acc3[8];
        {
            const float4 bv = *(const float4*)&bias3_s[nbase3 + quad * 4];
            #pragma unroll
            for (int mt = 0; mt < 8; ++mt)
                acc3[mt] = (floatx4){bv.x, bv.y, bv.z, bv.w};
        }
        short8 aw3[2];
        aw3[0] = aw3p;
        #pragma unroll
        for (int ks = 0; ks < 8; ++ks) {
            const int cur = ks & 1, nxt = cur ^ 1;
            if (ks < 7) {
                const int kb = (ks + 1) * 32 + quad * 8;
                aw3[nxt] = *(const short8*)(w3bf + (nbase3 + l15) * HD + kb);
            }
            const int kb0 = ks * 32 + quad * 8;
            #pragma unroll
            for (int chunk = 0; chunk < 2; ++chunk) {
                short8 bh[4];
                #pragma unroll
                for (int m = 0; m < 4; ++m)
                    bh[m] = *(const short8*)&hA[(chunk * 4 + m) * 16 + l15][kb0];
                #pragma unroll
                for (int m = 0; m < 4; ++m)
                    acc3[chunk * 4 + m] = __builtin_amdgcn_mfma_f32_16x16x32_bf16(
                        aw3[cur], bh[m], acc3[chunk * 4 + m], 0, 0, 0);
            }
        }
        // Prefetch all W4 frags (acc3 dying frees regs; in flight across barriers 5+6).
        short8 aw4p[4];
        #pragma unroll
        for (int ks = 0; ks < 4; ++ks)
            aw4p[ks] = *(const short8*)(w4bf + l15 * HD2 + ks * 32 + quad * 8);
        // Early silu+pack.
        uint2 pk3[8];
        #pragma unroll
        for (int mt = 0; mt < 8; ++mt)
            pk3[mt] = SILU_PACK(acc3[mt]);
        __syncthreads();   // barrier 5: all reads of h2 done
        #pragma unroll
        for (int mt = 0; mt < 8; ++mt)
            *(uint2*)&hA[mt * 16 + l15][nbase3 + quad * 4] = pk3[mt];
        __syncthreads();   // barrier 6: h3 complete

        // ---- Layer 4 + softmax (MFMA, K=128, A=W4pad B=h3): wave owns rows [wv*16, +16) ----
        floatx4 acc4;
        #pragma unroll
        for (int i = 0; i < 4; ++i) {
            const int rrow = quad * 4 + i;
            acc4[i] = (rrow < G) ? b4[rrow] : 0.0f;
        }
        #pragma unroll
        for (int ks = 0; ks < 4; ++ks) {
            const int kb = ks * 32 + quad * 8;
            const short8 bh4 = *(const short8*)&hA[wv * 16 + l15][kb];
            acc4 = __builtin_amdgcn_mfma_f32_16x16x32_bf16(aw4p[ks], bh4, acc4, 0, 0, 0);
        }
        if (lane < 16) {   // quad 0: regs 0..2 = logits 0..2 for batch row wv*16+l15
            const float l0 = acc4[0] * beta;
            const float l1 = acc4[1] * beta;
            const float l2 = acc4[2] * beta;
            const float m  = fmaxf(l0, fmaxf(l1, l2));
            const float e0 = __expf(l0 - m), e1 = __expf(l1 - m), e2 = __expf(l2 - m);
            const float inv = fast_rcp(e0 + e1 + e2);
            const int r = row0 + wv * 16 + l15;
            out[r * 3 + 0] = e0 * inv;
            out[r * 3 + 1] = e1 * inv;
            out[r * 3 + 2] = e2 * inv;
        }
    }
    #undef SILU_PACK
}

extern "C" void kernel_launch(void* const* d_in, const int* in_sizes, int n_in,
                              void* d_out, int out_size, void* d_ws, size_t ws_size,
                              hipStream_t stream) {
    (void)in_sizes; (void)n_in; (void)out_size; (void)ws_size;
    const float* log_p  = (const float*)d_in[0];
    const float* log_y  = (const float*)d_in[1];
    const float* log_xb = (const float*)d_in[2];
    const float* log_q  = (const float*)d_in[3];
    const float* W1 = (const float*)d_in[4];
    const float* b1 = (const float*)d_in[5];
    const float* W2 = (const float*)d_in[6];
    const float* b2 = (const float*)d_in[7];
    const float* W3 = (const float*)d_in[8];
    const float* b3 = (const float*)d_in[9];
    const float* W4 = (const float*)d_in[10];
    const float* b4 = (const float*)d_in[11];
    const float* lb = (const float*)d_in[12];
    const float* ld = (const float*)d_in[13];

    unsigned short* w2bf = (unsigned short*)d_ws;      // 65536 elems
    unsigned short* w3bf = w2bf + HD * HD;             // 32768 elems
    unsigned short* w1bf = w3bf + HD2 * HD;            // 8192 elems
    unsigned short* w4bf = w1bf + HD * 32;             // 2048 elems  (total 212 KB)

    convert_w_kernel<<<256, 256, 0, stream>>>(W1, W2, W3, W4, w1bf, w2bf, w3bf, w4bf);
    mlp_kernel<<<B_TOTAL / ROWS, NTHREADS, 0, stream>>>(
        log_p, log_y, log_xb, log_q, b1, b2, b3, b4, lb, ld,
        w1bf, w2bf, w3bf, w4bf, (float*)d_out);
}